// Round 1
// baseline (706.586 us; speedup 1.0000x reference)
//
#include <hip/hip_runtime.h>

// ParabolicPool2D: out[b,c,i,j] = max_{p,q in 3x3} f[b,c,2i+p,2j+q] + h[c,p,q]
// h[c,p,q] = -zc[p,q]*t[c], zc = [[1,.5,1],[.5,0,.5],[1,.5,1]]
// Group taps by additive constant: center (+0), 4 edges (-0.5t), 4 corners (-t).
// max is monotone under fp rounding, so group-max-then-add == per-tap-add-then-max bitwise.

constexpr int Bn = 16, Cn = 128, Hn = 256, Wn = 256;
constexpr int OH = 127, OW = 127;

__global__ __launch_bounds__(256) void pp2d_kernel(const float* __restrict__ f,
                                                   const float* __restrict__ t,
                                                   float* __restrict__ out) {
    // grid: x = y-tiles (fast-varying -> vertical L2 locality), y = b*C+c
    const int bc = blockIdx.y;                       // 0 .. B*C-1
    const int c  = bc & (Cn - 1);
    const int i  = blockIdx.x * blockDim.y + threadIdx.y;  // output row
    if (i >= OH) return;
    const int tx = threadIdx.x;                      // 0..63
    const int j0 = tx * 2;                           // first output col (<=126, always valid)
    const bool has2 = (j0 + 1) < OW;

    const float tc   = t[c];
    const float eAdd = -0.5f * tc;   // edge taps
    const float kAdd = -tc;          // corner taps

    const float* frow = f + ((size_t)bc * Hn + (size_t)(2 * i)) * Wn;
    const int c0 = 4 * tx;           // first input col; c0+3 <= 255 always

    const float4 v0 = *(const float4*)(frow + c0);
    const float4 v1 = *(const float4*)(frow + Wn + c0);
    const float4 v2 = *(const float4*)(frow + 2 * Wn + c0);
    float s0 = 0.f, s1 = 0.f, s2 = 0.f;
    if (has2) {                      // col c0+4 (OOB only when tx==63)
        s0 = frow[c0 + 4];
        s1 = frow[Wn + c0 + 4];
        s2 = frow[2 * Wn + c0 + 4];
    }

    // output j0 uses input cols c0..c0+2 -> (x,y,z)
    const float center0 = v1.y;
    const float edge0   = fmaxf(fmaxf(v0.y, v2.y), fmaxf(v1.x, v1.z));
    const float corn0   = fmaxf(fmaxf(v0.x, v0.z), fmaxf(v2.x, v2.z));
    const float o0 = fmaxf(center0, fmaxf(edge0 + eAdd, corn0 + kAdd));

    float* orow = out + ((size_t)bc * OH + i) * OW;
    if (has2) {
        // output j0+1 uses input cols c0+2..c0+4 -> (z,w,s)
        const float center1 = v1.w;
        const float edge1   = fmaxf(fmaxf(v0.w, v2.w), fmaxf(v1.z, s1));
        const float corn1   = fmaxf(fmaxf(v0.z, s0), fmaxf(v2.z, s2));
        const float o1 = fmaxf(center1, fmaxf(edge1 + eAdd, corn1 + kAdd));
        orow[j0]     = o0;
        orow[j0 + 1] = o1;
    } else {
        orow[j0] = o0;
    }
}

extern "C" void kernel_launch(void* const* d_in, const int* in_sizes, int n_in,
                              void* d_out, int out_size, void* d_ws, size_t ws_size,
                              hipStream_t stream) {
    const float* f = (const float*)d_in[0];
    const float* t = (const float*)d_in[1];
    float* out = (float*)d_out;

    dim3 block(64, 4, 1);
    dim3 grid((OH + 3) / 4, Bn * Cn, 1);   // (32, 2048)
    pp2d_kernel<<<grid, block, 0, stream>>>(f, t, out);
}